// Round 6
// baseline (285.236 us; speedup 1.0000x reference)
//
#include <hip/hip_runtime.h>

#define TT 512
#define BB 1024
#define VV 96
#define LL 48

__device__ __forceinline__ int f2i(float x) { return __float_as_int(x); }
__device__ __forceinline__ float i2f(int x) { return __int_as_float(x); }

template <int CTRL, int RM, int BM, bool BC>
__device__ __forceinline__ float dppf(float old, float src) {
    return i2f(__builtin_amdgcn_update_dpp(f2i(old), f2i(src), CTRL, RM, BM, BC));
}

// Full-wave sum via DPP butterfly (verified); broadcast via lane 63.
__device__ __forceinline__ float wave_sum(float v) {
    v += dppf<0xB1, 0xF, 0xF, true>(0.f, v);   // quad_perm [1,0,3,2]
    v += dppf<0x4E, 0xF, 0xF, true>(0.f, v);   // quad_perm [2,3,0,1]
    v += dppf<0x141, 0xF, 0xF, true>(0.f, v);  // row_half_mirror
    v += dppf<0x140, 0xF, 0xF, true>(0.f, v);  // row_mirror
    v += dppf<0x142, 0xA, 0xF, false>(0.f, v); // row_bcast15
    v += dppf<0x143, 0xC, 0xF, false>(0.f, v); // row_bcast31
    return i2f(__builtin_amdgcn_readlane(f2i(v), 63));
}

// Full-wave max (nonnegative inputs; old=0 is neutral).
__device__ __forceinline__ float wave_max(float v) {
    v = fmaxf(v, dppf<0xB1, 0xF, 0xF, true>(0.f, v));
    v = fmaxf(v, dppf<0x4E, 0xF, 0xF, true>(0.f, v));
    v = fmaxf(v, dppf<0x141, 0xF, 0xF, true>(0.f, v));
    v = fmaxf(v, dppf<0x140, 0xF, 0xF, true>(0.f, v));
    v = fmaxf(v, dppf<0x142, 0xA, 0xF, false>(0.f, v));
    v = fmaxf(v, dppf<0x143, 0xC, 0xF, false>(0.f, v));
    return i2f(__builtin_amdgcn_readlane(f2i(v), 63));
}

// Packed-pair state layout: lane l owns states (2l, 2l+1); lanes 0..48 cover
// all 97 extended states (state 96 = lane 48 even slot; Ao(48) and lanes>=49
// are structurally zero). Odd state 2l+1 has label lb[l] -> its emission is a
// DIRECT per-lane load row[lb[l]] (no ds_bpermute anywhere); blank emission is
// readfirstlane(exp(row[0])). Forward needs 1 DPP/step, backward 2.
// Two waves per batch element (verified round-5 meet-in-the-middle):
//   wave 0: forward  alpha_255 = M_255..M_0 * delta0       (256 steps)
//   wave 1: backward v = M_256^T..M_511^T * (e95+e96)      (256 steps)
// loss = 512*ln96 - (S2a+S2b)*ln2 - ln(dot(alpha_255, v)); dot in f64 with
// bit-level exponent peel (round-4 underflow fix, verified round 5).
__global__ __launch_bounds__(128) void ctc_split_packed(
        const int* __restrict__ labels,
        const float* __restrict__ yp,
        float* __restrict__ loss) {
    const int b = blockIdx.x;
    const int tid = threadIdx.x;
    const int wid = tid >> 6;
    const int l = tid & 63;
    const int* lb = labels + b * LL;

    const int ll = (l < 48) ? l : 47;        // clamped label index / f2 slot
    const int lbl = lb[ll];
    const bool lab = (l < 48);               // lane owns a real odd state
    // forward: skip into state 2l+1 from 2l-1 iff lb[l] != lb[l-1]
    const bool skF = (l >= 1) && lab && (lb[l - 1] != lbl);
    // backward: contribution of w[2l+3] to v'[2l+1] iff lb[l+1] != lb[l]
    const bool skB = (l < 47) && (lb[l + 1] != lbl);

    const float* base = yp + (size_t)b * VV; // row t = base + t*rstep
    const size_t rstep = (size_t)BB * VV;

    float2 ringD[8];   // denominator float2 (row[2ll], row[2ll+1])
    float  ringL[8];   // own-label logit row[lb[ll]]
    float Ae, Ao;      // packed states (2l, 2l+1)
    int S2 = 0;
    float Eb, El;      // blank / own-label emission (96-scaled softmax)

#define LOADROW(ROW, SLOT) { \
        const float* rp_ = base + (size_t)(ROW) * rstep; \
        ringD[SLOT] = *(const float2*)(rp_ + 2 * ll); \
        ringL[SLOT] = rp_[lbl]; }

#define STAGEA(SLOT) { \
        float ex0 = __expf(ringD[SLOT].x), ex1 = __expf(ringD[SLOT].y); \
        float exl = __expf(ringL[SLOT]); \
        float se = lab ? (ex0 + ex1) : 0.f; \
        float tot = wave_sum(se); \
        float r96 = 96.0f * __builtin_amdgcn_rcpf(tot); \
        Eb = i2f(__builtin_amdgcn_readfirstlane(f2i(ex0))) * r96; \
        El = lab ? exl * r96 : 0.f; }

#define RENORM { \
        float vm = fmaxf(Ae, Ao); \
        float m = wave_max(vm); \
        int eb_ = (f2i(m) >> 23) & 0xFF; \
        float sc = i2f((254 - eb_) << 23); \
        Ae *= sc; Ao *= sc; \
        S2 += eb_ - 127; }

    __shared__ float sBe[64];
    __shared__ float sBo[64];
    __shared__ int sS2b;

    if (wid == 0) {
        // ---------------- forward chunk: rows 0..255 ----------------
        #pragma unroll
        for (int j = 0; j < 8; ++j) LOADROW(j, j)
        // delta at state 0; first update with E(0) reproduces alpha0 exactly
        Ae = (l == 0) ? 1.f : 0.f;
        Ao = 0.f;
        STAGEA(0)                              // E(row 0)
        LOADROW(8, 0)
        for (int o = 0; o < 8; ++o) {
            for (int u = 0; u < 4; ++u) {
                #pragma unroll
                for (int tt = 0; tt < 8; ++tt) {
                    const int k = 32 * o + 8 * u + tt;   // k & 7 == tt
                    // alpha'[2l]   = (alpha[2l]   + alpha[2l-1]) * Eb
                    // alpha'[2l+1] = (alpha[2l+1] + alpha[2l] + skF*alpha[2l-1]) * El
                    float sh = dppf<0x138, 0xF, 0xF, false>(0.f, Ao); // wave_shr1
                    float AeN = (Ae + sh) * Eb;
                    float AoN = (Ao + Ae + (skF ? sh : 0.f)) * El;
                    Ae = AeN; Ao = AoN;
                    STAGEA((tt + 1) & 7)                 // E(row k+1)
                    int kr = k + 9; if (kr > 255) kr = 255;
                    LOADROW(kr, (tt + 1) & 7)
                }
            }
            RENORM
        }
    } else {
        // ---------------- backward chunk: rows 511..256 ----------------
        #pragma unroll
        for (int j = 0; j < 8; ++j) LOADROW(511 - j, j)
        Ae = (l == 48) ? 1.f : 0.f;   // state 96
        Ao = (l == 47) ? 1.f : 0.f;   // state 95
        STAGEA(0)                     // E(row 511)
        LOADROW(511 - 8, 0)
        for (int o = 0; o < 8; ++o) {
            for (int u = 0; u < 4; ++u) {
                #pragma unroll
                for (int tt = 0; tt < 8; ++tt) {
                    const int k = 32 * o + 8 * u + tt;   // applies row 511-k
                    // w = E .* v;  v'[2l] = w[2l] + w[2l+1]
                    //              v'[2l+1] = w[2l+1] + w[2l+2] + skB*w[2l+3]
                    float wE = Ae * Eb;
                    float wO = Ao * El;
                    float sE = dppf<0x130, 0xF, 0xF, false>(0.f, wE); // wave_shl1
                    float sO = dppf<0x130, 0xF, 0xF, false>(0.f, wO);
                    Ae = wE + wO;
                    Ao = wO + sE + (skB ? sO : 0.f);
                    STAGEA((tt + 1) & 7)                 // E(row 511-(k+1))
                    int kr = k + 9; if (kr > 255) kr = 255;
                    LOADROW(511 - kr, (tt + 1) & 7)
                }
            }
            RENORM
        }
        sBe[l] = Ae;
        sBo[l] = Ao;
        if (l == 0) sS2b = S2;
    }
    __syncthreads();
    if (wid == 0) {
        // f64 dot (components can f32-underflow: ~2^-130; f64 min 2^-1022)
        double pd = (double)Ae * (double)sBe[l] + (double)Ao * (double)sBo[l];
        #pragma unroll
        for (int m = 1; m < 64; m <<= 1) pd += __shfl_xor(pd, m);
        if (l == 0) {
            long long ud = __double_as_longlong(pd);
            int eb = (int)((ud >> 52) & 0x7FF);             // biased exponent
            double md = __longlong_as_double(
                (ud & 0x000FFFFFFFFFFFFFLL) | 0x3FF0000000000000LL); // [1,2)
            int s2tot = S2 + sS2b + (eb - 1023);
            loss[b] = 2336.946274031532f
                    - (float)s2tot * 0.6931471805599453f
                    - __logf((float)md);
        }
    }
#undef LOADROW
#undef STAGEA
#undef RENORM
}

__global__ __launch_bounds__(256) void ctc_mean_kernel(
        const float* __restrict__ loss, float* __restrict__ out) {
    const int tid = threadIdx.x;
    float v = loss[tid] + loss[tid + 256] + loss[tid + 512] + loss[tid + 768];
    #pragma unroll
    for (int m = 1; m < 64; m <<= 1) v += __shfl_xor(v, m);
    __shared__ float part[4];
    if ((tid & 63) == 0) part[tid >> 6] = v;
    __syncthreads();
    if (tid == 0) out[0] = (part[0] + part[1] + part[2] + part[3]) * (1.0f / (float)BB);
}

extern "C" void kernel_launch(void* const* d_in, const int* in_sizes, int n_in,
                              void* d_out, int out_size, void* d_ws, size_t ws_size,
                              hipStream_t stream) {
    const int* y_true = (const int*)d_in[0];     // [B, L] int32
    const float* y_pred = (const float*)d_in[1]; // [T, B, V] float32
    float* out = (float*)d_out;
    float* lossbuf = (float*)d_ws;               // [B] floats

    ctc_split_packed<<<BB, 128, 0, stream>>>(y_true, y_pred, lossbuf);
    ctc_mean_kernel<<<1, 256, 0, stream>>>(lossbuf, out);
}